// Round 2
// baseline (98.324 us; speedup 1.0000x reference)
//
#include <hip/hip_runtime.h>
#include <hip/hip_bf16.h>
#include <cstdint>

typedef __attribute__((ext_vector_type(4))) float f32x4;
typedef __attribute__((ext_vector_type(8))) short short8;

#define DEVI __device__ __forceinline__

// float -> bf16 with round-to-nearest-even
DEVI uint16_t f2bf(float v) {
    union { float f; uint32_t u; } c; c.f = v;
    uint32_t u = c.u + 0x7FFFu + ((c.u >> 16) & 1u);
    return (uint16_t)(u >> 16);
}
DEVI float bflo(uint32_t u) { union { uint32_t u; float f; } c; c.u = u << 16; return c.f; }
DEVI float bfhi(uint32_t u) { union { uint32_t u; float f; } c; c.u = u & 0xFFFF0000u; return c.f; }

// async global->LDS, 16 bytes per lane
DEVI void async16(const uint16_t* g, uint16_t* l) {
    __builtin_amdgcn_global_load_lds((const __attribute__((address_space(1))) void*)g,
                                     (__attribute__((address_space(3))) void*)l, 16, 0, 0);
}

// ---------------- prep: features (C,H,W) f32 -> featT (H,W,C) bf16 ----------------
__global__ __launch_bounds__(256) void prep_feat(const float* __restrict__ f,
                                                 uint16_t* __restrict__ featT) {
    __shared__ uint16_t s[128 * 130];   // pad 130 to break bank conflicts on transpose
    const int x = blockIdx.x;           // H index
    const float* fx = f + x * 128;      // f[c*16384 + x*128 + y]
    for (int i = threadIdx.x; i < 16384; i += 256) {
        int c = i >> 7, y = i & 127;
        s[y * 130 + c] = f2bf(fx[c * 16384 + y]);
    }
    __syncthreads();
    uint16_t* o = featT + x * 16384;    // featT[(x*128 + y)*128 + c]
    for (int i = threadIdx.x; i < 16384; i += 256) {
        int y = i >> 7, c = i & 127;
        o[i] = s[y * 130 + c];
    }
}

// ---------------- convert W1,W2 (1024x1024 f32, row-major (out,in)) -> bf16 ----------------
__global__ __launch_bounds__(256) void cvt_w(const float* __restrict__ W1, uint16_t* __restrict__ W1b,
                                             const float* __restrict__ W2, uint16_t* __restrict__ W2b) {
    int i = blockIdx.x * 256 + threadIdx.x;   // 262144 threads x 4 elems = 1M each
    float4 a = ((const float4*)W1)[i];
    float4 b = ((const float4*)W2)[i];
    ushort4 pa = { f2bf(a.x), f2bf(a.y), f2bf(a.z), f2bf(a.w) };
    ushort4 pb = { f2bf(b.x), f2bf(b.y), f2bf(b.z), f2bf(b.w) };
    ((ushort4*)W1b)[i] = pa;
    ((ushort4*)W2b)[i] = pb;
}

// ---------------- extract + bilinear + maxpool(4) -> flat (8192 x 1024) bf16 ----------------
// flat[n][c*8 + g] = max over 4 points of bilinear sample of channel c
__global__ __launch_bounds__(256) void extract_k(const float4* __restrict__ lines,
                                                 const uint16_t* __restrict__ featT,
                                                 uint16_t* __restrict__ flat) {
    const int n = blockIdx.x;
    const int tid = threadIdx.x;
    const int lane = tid & 63, wave = tid >> 6;
    const float4 ln = lines[n];           // (U.x, U.y, V.x, V.y)
    __shared__ uint16_t ps[1024];
    const uint16_t* fb = featT + lane * 2;     // channels 2*lane, 2*lane+1

    for (int g2 = 0; g2 < 2; ++g2) {
        const int g = wave * 2 + g2;           // pool group 0..7
        float m0 = -1e30f, m1 = -1e30f;
#pragma unroll
        for (int pp = 0; pp < 4; ++pp) {
            const float t = (float)(g * 4 + pp) * (1.0f / 31.0f);
            const float x = ln.x * t + ln.z * (1.0f - t) - 0.5f;   // indexes H
            const float y = ln.y * t + ln.w * (1.0f - t) - 0.5f;   // indexes W
            const float x0f = fminf(fmaxf(floorf(x), 0.0f), 127.0f);
            const float y0f = fminf(fmaxf(floorf(y), 0.0f), 127.0f);
            const float x1f = fminf(x0f + 1.0f, 127.0f);
            const float y1f = fminf(y0f + 1.0f, 127.0f);
            const int x0 = (int)x0f, x1 = (int)x1f, y0 = (int)y0f, y1 = (int)y1f;
            const float wx1 = x - x0f, wx0 = x1f - x;
            const float wy1 = y - y0f, wy0 = y1f - y;
            const uint32_t u00 = *(const uint32_t*)(fb + ((x0 * 128 + y0) << 7));
            const uint32_t u01 = *(const uint32_t*)(fb + ((x0 * 128 + y1) << 7));
            const uint32_t u10 = *(const uint32_t*)(fb + ((x1 * 128 + y0) << 7));
            const uint32_t u11 = *(const uint32_t*)(fb + ((x1 * 128 + y1) << 7));
            const float w00 = wy0 * wx0, w01 = wy1 * wx0, w10 = wy0 * wx1, w11 = wy1 * wx1;
            const float a = bflo(u00) * w00 + bflo(u01) * w01 + bflo(u10) * w10 + bflo(u11) * w11;
            const float b = bfhi(u00) * w00 + bfhi(u01) * w01 + bfhi(u10) * w10 + bfhi(u11) * w11;
            m0 = fmaxf(m0, a);
            m1 = fmaxf(m1, b);
        }
        ps[lane * 16 + g]     = f2bf(m0);   // channel 2*lane
        ps[lane * 16 + 8 + g] = f2bf(m1);   // channel 2*lane+1
    }
    __syncthreads();
    // coalesced 2KB row write
    *(uint2*)(flat + (size_t)n * 1024 + tid * 4) = ((const uint2*)ps)[tid];
}

// ---------------- bf16 GEMM (m97 structure): out[m][n] = relu(sum_k A[m][k]*B[n][k] + bias[n]) ----------------
// A: MxK row-major bf16, B: NxK row-major bf16 (i.e. W as given, (out,in))
template <int RELU>
__global__ __launch_bounds__(256) void gemm_bt(const uint16_t* __restrict__ A,
                                               const uint16_t* __restrict__ B,
                                               const float* __restrict__ bias,
                                               uint16_t* __restrict__ Co,
                                               int M, int N, int K) {
    __shared__ uint16_t As[128 * 32];
    __shared__ uint16_t Bs[128 * 32];
    const int tid = threadIdx.x;
    const int lane = tid & 63, wave = tid >> 6;
    const int nbm = M >> 7;
    const int bm = blockIdx.x % nbm;
    const int bn = blockIdx.x / nbm;
    const int wr = wave >> 1, wc = wave & 1;       // 2x2 waves, each 64x64
    const int l15 = lane & 15, l16 = lane >> 4;

    f32x4 acc[4][4] = {};

    const uint16_t* Ag = A + (size_t)(bm * 128) * K;
    const uint16_t* Bg = B + (size_t)(bn * 128) * K;

    for (int kt = 0; kt < K; kt += 32) {
        if (kt) __syncthreads();
#pragma unroll
        for (int i = 0; i < 2; ++i) {
            const int c = i * 256 + tid;           // chunk 0..511 (16B each)
            const int row = c >> 2, off = (c & 3) * 8;
            async16(Ag + (size_t)row * K + kt + off, &As[c * 8]);
            async16(Bg + (size_t)row * K + kt + off, &Bs[c * 8]);
        }
        __syncthreads();
        short8 a[4], b[4];
#pragma unroll
        for (int fm = 0; fm < 4; ++fm)
            a[fm] = *(const short8*)&As[(wr * 64 + fm * 16 + l15) * 32 + l16 * 8];
#pragma unroll
        for (int fn = 0; fn < 4; ++fn)
            b[fn] = *(const short8*)&Bs[(wc * 64 + fn * 16 + l15) * 32 + l16 * 8];
#pragma unroll
        for (int fm = 0; fm < 4; ++fm)
#pragma unroll
            for (int fn = 0; fn < 4; ++fn)
                acc[fm][fn] = __builtin_amdgcn_mfma_f32_16x16x32_bf16(a[fm], b[fn], acc[fm][fn], 0, 0, 0);
    }

#pragma unroll
    for (int fm = 0; fm < 4; ++fm) {
        const int row = bm * 128 + wr * 64 + fm * 16 + l16 * 4;
#pragma unroll
        for (int fn = 0; fn < 4; ++fn) {
            const int col = bn * 128 + wc * 64 + fn * 16 + l15;
            const float bv = bias[col];
#pragma unroll
            for (int r = 0; r < 4; ++r) {
                float v = acc[fm][fn][r] + bv;
                if (RELU) v = fmaxf(v, 0.0f);
                Co[(size_t)(row + r) * N + col] = f2bf(v);
            }
        }
    }
}

// ---------------- thin GEMM3: out[m][j] = sum_k h2[m][k]*W3[j][k] + b3[j], fp32 ----------------
__global__ __launch_bounds__(256) void gemm3_k(const uint16_t* __restrict__ h2,
                                               const float* __restrict__ W3,
                                               const float* __restrict__ b3,
                                               float* __restrict__ out) {
    const int wave = threadIdx.x >> 6, lane = threadIdx.x & 63;
    const int m = blockIdx.x * 4 + wave;
    const uint4* hr = (const uint4*)(h2 + (size_t)m * 1024 + lane * 16);
    const uint4 u0 = hr[0], u1 = hr[1];
    float h[16];
    h[0] = bflo(u0.x); h[1] = bfhi(u0.x); h[2] = bflo(u0.y); h[3] = bfhi(u0.y);
    h[4] = bflo(u0.z); h[5] = bfhi(u0.z); h[6] = bflo(u0.w); h[7] = bfhi(u0.w);
    h[8]  = bflo(u1.x); h[9]  = bfhi(u1.x); h[10] = bflo(u1.y); h[11] = bfhi(u1.y);
    h[12] = bflo(u1.z); h[13] = bfhi(u1.z); h[14] = bflo(u1.w); h[15] = bfhi(u1.w);
    float acc[4];
#pragma unroll
    for (int j = 0; j < 4; ++j) {
        const float4* wr = (const float4*)(W3 + j * 1024 + lane * 16);
        const float4 w0 = wr[0], w1 = wr[1], w2 = wr[2], w3 = wr[3];
        float s;
        s  = h[0] * w0.x;  s += h[1] * w0.y;  s += h[2] * w0.z;  s += h[3] * w0.w;
        s += h[4] * w1.x;  s += h[5] * w1.y;  s += h[6] * w1.z;  s += h[7] * w1.w;
        s += h[8] * w2.x;  s += h[9] * w2.y;  s += h[10] * w2.z; s += h[11] * w2.w;
        s += h[12] * w3.x; s += h[13] * w3.y; s += h[14] * w3.z; s += h[15] * w3.w;
        acc[j] = s;
    }
#pragma unroll
    for (int off = 32; off >= 1; off >>= 1) {
#pragma unroll
        for (int j = 0; j < 4; ++j) acc[j] += __shfl_xor(acc[j], off);
    }
    if (lane == 0) {
        float4 o = { acc[0] + b3[0], acc[1] + b3[1], acc[2] + b3[2], acc[3] + b3[3] };
        *(float4*)(out + (size_t)m * 4) = o;
    }
}

extern "C" void kernel_launch(void* const* d_in, const int* in_sizes, int n_in,
                              void* d_out, int out_size, void* d_ws, size_t ws_size,
                              hipStream_t stream) {
    const float* feats = (const float*)d_in[0];   // 128*128*128 (C,H,W)
    const float* lines = (const float*)d_in[1];   // 8192*4
    const float* W1 = (const float*)d_in[2];      // 1024*1024
    const float* b1 = (const float*)d_in[3];
    const float* W2 = (const float*)d_in[4];
    const float* b2 = (const float*)d_in[5];
    const float* W3 = (const float*)d_in[6];      // 4*1024
    const float* b3 = (const float*)d_in[7];
    float* out = (float*)d_out;

    char* ws = (char*)d_ws;
    uint16_t* featT = (uint16_t*)(ws);                        // 4 MB  (H,W,C) bf16
    uint16_t* W1b   = (uint16_t*)(ws + (4u << 20));           // 2 MB
    uint16_t* W2b   = (uint16_t*)(ws + (6u << 20));           // 2 MB
    uint16_t* flat  = (uint16_t*)(ws + (8u << 20));           // 16 MB (also reused for h2)
    uint16_t* h1    = (uint16_t*)(ws + (24u << 20));          // 16 MB -> total 40 MB

    prep_feat<<<128, 256, 0, stream>>>(feats, featT);
    cvt_w<<<1024, 256, 0, stream>>>(W1, W1b, W2, W2b);
    extract_k<<<8192, 256, 0, stream>>>((const float4*)lines, featT, flat);
    gemm_bt<1><<<512, 256, 0, stream>>>(flat, W1b, b1, h1, 8192, 1024, 1024);
    gemm_bt<1><<<512, 256, 0, stream>>>(h1, W2b, b2, flat, 8192, 1024, 1024);
    gemm3_k<<<2048, 256, 0, stream>>>(flat, W3, b3, out);
}